// Round 15
// baseline (107.556 us; speedup 1.0000x reference)
//
#include <hip/hip_runtime.h>
#include <cstddef>

#define NB   8
#define NPTS 4096
#define KNN  16
#define FCAP 64    // per-query collected-candidate capacity

typedef _Float16 h2 __attribute__((ext_vector_type(2)));
typedef _Float16 h8 __attribute__((ext_vector_type(8)));
typedef float    f4 __attribute__((ext_vector_type(4)));
typedef float    f16f __attribute__((ext_vector_type(16)));

static __device__ __forceinline__ h2 pk2(float a, float b) {
    return __builtin_bit_cast(h2, __builtin_amdgcn_cvt_pkrtz(a, b));
}
static __device__ __forceinline__ unsigned bch(h2 v) {
    return __builtin_bit_cast(unsigned, v);
}

#if __has_builtin(__builtin_amdgcn_fmed3f)
static __device__ __forceinline__ float MED3(float a, float b, float c) {
    return __builtin_amdgcn_fmed3f(a, b, c);
}
#else
static __device__ __forceinline__ float MED3(float a, float b, float c) {
    return fmaxf(fminf(a, b), fminf(fmaxf(a, b), c));
}
#endif

// Exact f32 distance (sq-form). Same fmaf nesting as prep's sq -> self-dist
// is exactly 0. Used ONLY for the exact candidate distances.
static __device__ __forceinline__ float dist2(float4 Q, float4 p) {
    float dot = fmaf(Q.z, p.z, fmaf(Q.y, p.y, Q.x * p.x));
    return fmaf(-2.0f, dot, Q.w + p.w);
}

// ---------------------------------------------------------------------------
// Kernel P: pack pts4[b][n] = (x, y, z, x*x+y*y+z*z) from xyz[B][3][N]
// ---------------------------------------------------------------------------
__global__ __launch_bounds__(256) void prep_kernel(const float* __restrict__ xyz,
                                                   float4* __restrict__ pts4) {
    int i = blockIdx.x * 256 + threadIdx.x;
    int b = i >> 12;
    int n = i & (NPTS - 1);
    const float* base = xyz + (size_t)b * 3 * NPTS;
    float x = base[n];
    float y = base[NPTS + n];
    float z = base[2 * NPTS + n];
    float sq = fmaf(z, z, fmaf(y, y, x * x));   // same nesting as dist2's dot
    pts4[i] = make_float4(x, y, z, sq);
}

// ---------------------------------------------------------------------------
// Kernel A: exact 16-NN, 32x32x16 MFMA pruning keys (round-14 structure) with
//  (1) LDS diet 66.5->49.7 KB: merge level 1 sorts IN PLACE in `partials`
//      (mbuf eliminated); `fdist` overlays the Pm staging buffer (dead after
//      phase 2, barrier-separated). Removes any 2-blocks/CU residency doubt.
//  (2) phase-2 mask-compact push: per-lane 16-bit hit mask + single
//      atomicAdd(popc) reservation + ffs-extract (~70 inst/tile vs ~190).
// Selection math, per-query tight E, exact f32 sweep, lexicographic final
// select (== jax.lax.top_k tie-break): all identical to round 14.
// ---------------------------------------------------------------------------
__global__ __launch_bounds__(1024, 8) void knn_kernel(const float4* __restrict__ pts4,
                                                      int* __restrict__ idxout) {
    __shared__ uint2 Pm[NPTS];                        // 32 KB; fdist overlays later
    __shared__ char  sbuf[16384];                     // 16 KB partials -> fidx
    __shared__ float tauv[64];
    __shared__ int   qcnt[64];
    __shared__ unsigned pmaxu, smaxu;

    float*    partials = (float*)sbuf;                // [64 slots][64 q] 16 KB
    unsigned* fidx     = (unsigned*)sbuf;             // [FCAP][64 q]    16 KB
    float*    fdist    = (float*)Pm;                  // [FCAP][64 q]    16 KB

    int tid = threadIdx.x;
    int b   = blockIdx.y;
    const float4* pb = pts4 + (size_t)b * NPTS;

    if (tid == 0) { pmaxu = 0u; smaxu = 0u; }
    __syncthreads();

    // ---- stage (xh,yh|zh,sh); reduce exact pmax/smax of the batch ----
    {
        float lm = 0.0f, ls = 0.0f;
        for (int j = tid; j < NPTS; j += 1024) {
            float4 p = pb[j];
            lm = fmaxf(lm, fmaxf(fabsf(p.x), fmaxf(fabsf(p.y), fabsf(p.z))));
            ls = fmaxf(ls, p.w);
            h2 lo = { (_Float16)p.x, (_Float16)p.y };
            h2 hi = { (_Float16)p.z, (_Float16)p.w };
            Pm[j].x = bch(lo);
            Pm[j].y = bch(hi);
        }
        atomicMax(&pmaxu, __builtin_bit_cast(unsigned, lm));   // f32>=0: uint order
        atomicMax(&smaxu, __builtin_bit_cast(unsigned, ls));
    }

    int wave = tid >> 6, lane = tid & 63;
    int g  = wave >> 3;           // query half 0..1 (32 q each)
    int c  = wave & 7;            // candidate chunk 0..7 (512 cands)
    int col = lane & 31;          // A-row / B-col / D-col
    int hl  = lane >> 5;          // lane half (k-slot group / D row group)
    int q  = g * 32 + col;        // 0..63
    int nq = (blockIdx.x << 6) + q;
    int cbase = c * 512;

    float4 qf = pb[nq];
    float uxf = -2.0f * qf.x, uyf = -2.0f * qf.y, uzf = -2.0f * qf.z;  // exact
    _Float16 uxh = (_Float16)uxf, uyh = (_Float16)uyf, uzh = (_Float16)uzf;
    _Float16 uxl = (_Float16)(uxf - (float)uxh);
    _Float16 uyl = (_Float16)(uyf - (float)uyh);
    _Float16 uzl = (_Float16)(uzf - (float)uzh);
    uint4 bu = {0u, 0u, 0u, 0u};
    if (hl == 0) {
        h2 b01 = {uxh, uyh}, b23 = {uzh, (_Float16)1.0f};
        h2 b45 = {uxl, uyl}, b67 = {uzl, (_Float16)0.0f};
        bu.x = bch(b01); bu.y = bch(b23); bu.z = bch(b45); bu.w = bch(b67);
    }
    h8 bq = __builtin_bit_cast(h8, bu);
    __syncthreads();

    // ---- phase 1: 16 MFMA tiles (32 cands x 32 q), min16 + sorted-4 ----
    {
        float c0 = __builtin_inff(), c1 = c0, c2 = c0, c3 = c0;
#pragma unroll 2
        for (int t = 0; t < 16; ++t) {
            uint4 au = {0u, 0u, 0u, 0u};
            if (hl == 0) {
                uint2 pd = Pm[cbase + t * 32 + col];
                au.x = pd.x; au.y = pd.y; au.z = pd.x; au.w = pd.y;  // k0-3 & k4-7
            }
            f16f d = __builtin_amdgcn_mfma_f32_32x32x16_f16(
                __builtin_bit_cast(h8, au), bq, (f16f)0.0f, 0, 0, 0);
            float a0 = fminf(d[0], d[1]),   a1 = fminf(d[2], d[3]);
            float a2 = fminf(d[4], d[5]),   a3 = fminf(d[6], d[7]);
            float a4 = fminf(d[8], d[9]),   a5 = fminf(d[10], d[11]);
            float a6 = fminf(d[12], d[13]), a7 = fminf(d[14], d[15]);
            float b0 = fminf(a0, a1), b1 = fminf(a2, a3);
            float b2 = fminf(a4, a5), b3 = fminf(a6, a7);
            float rmin = fminf(fminf(b0, b1), fminf(b2, b3));
            float p0 = c0, p1 = c1, p2 = c2;
            c0 = fminf(p0, rmin);
            c1 = MED3(rmin, p0, c1);
            c2 = MED3(rmin, p1, c2);
            c3 = MED3(rmin, p2, c3);
        }
        int sb = (c * 2 + hl) * 4;
        partials[(sb + 0) * 64 + q] = c0;
        partials[(sb + 1) * 64 + q] = c1;
        partials[(sb + 2) * 64 + q] = c2;
        partials[(sb + 3) * 64 + q] = c3;
    }
    __syncthreads();

    // ---- merge level 1 (IN PLACE): 4 mergers/query x 16 slots -> sorted-16 ----
    if (tid < 256) {
        int qq = tid & 63, k = tid >> 6;
        float mb[16];
#pragma unroll
        for (int j = 0; j < 16; ++j) mb[j] = __builtin_inff();
        for (int s = 0; s < 16; ++s) {
            float v = partials[(k * 16 + s) * 64 + qq];
            float prev = mb[0];
            mb[0] = fminf(mb[0], v);
#pragma unroll
            for (int i = 1; i < 16; ++i) {
                float cur = mb[i];
                mb[i] = MED3(v, prev, cur);
                prev = cur;
            }
        }
#pragma unroll
        for (int j = 0; j < 16; ++j) partials[(k * 16 + j) * 64 + qq] = mb[j];
    }
    __syncthreads();

    // ---- merge level 2: 16th of 4 sorted lists; per-query tight bound ----
    if (tid < 64) {
        float mb[16];
#pragma unroll
        for (int j = 0; j < 16; ++j) mb[j] = __builtin_inff();
        for (int k = 0; k < 4; ++k) {
            for (int j = 0; j < 16; ++j) {
                float v = partials[(k * 16 + j) * 64 + tid];
                if (v >= mb[15]) break;             // ascending list
                float prev = mb[0];
                mb[0] = fminf(mb[0], v);
#pragma unroll
                for (int i = 1; i < 16; ++i) {
                    float cur = mb[i];
                    mb[i] = MED3(v, prev, cur);
                    prev = cur;
                }
            }
        }
        float4 q2 = pb[(blockIdx.x << 6) + tid];
        float sumq = fabsf(q2.x) + fabsf(q2.y) + fabsf(q2.z);
        float qn   = sqrtf(q2.w);                   // |q| (q2.w = |q|^2 >= 0)
        float pmax = __builtin_bit_cast(float, pmaxu);
        float smax = __builtin_bit_cast(float, smaxu);
        const float r11c = 4.8828125e-4f;           // 2^-11
        float tau = mb[15];
        float E0  = smax * r11c + 2.0f * sumq * pmax * r11c + 1.0e-3f;
        float rad2 = fmaxf(tau + 2.0f * E0 + q2.w, 0.0f);
        float R   = qn + sqrtf(rad2);
        float Eq  = (R * R + 2.0f * sumq * R) * r11c + 6.0e-4f;
        Eq = fminf(Eq, E0);
        tauv[tid] = tau + 2.0f * Eq;
        qcnt[tid] = 0;
    }
    __syncthreads();   // partials dead; sbuf reused as fidx

    // ---- phase 2: same MFMA (deterministic), mask-compact pushes ----
    {
        float tc = tauv[q];
#pragma unroll 1
        for (int t = 0; t < 16; ++t) {
            uint4 au = {0u, 0u, 0u, 0u};
            if (hl == 0) {
                uint2 pd = Pm[cbase + t * 32 + col];
                au.x = pd.x; au.y = pd.y; au.z = pd.x; au.w = pd.y;
            }
            f16f d = __builtin_amdgcn_mfma_f32_32x32x16_f16(
                __builtin_bit_cast(h8, au), bq, (f16f)0.0f, 0, 0, 0);
            unsigned m = 0u;
#pragma unroll
            for (int r = 0; r < 16; ++r) m |= (d[r] <= tc) ? (1u << r) : 0u;
            if (m) {
                int pos = atomicAdd(&qcnt[q], __popc(m));
                while (m) {
                    int r = __ffs(m) - 1;
                    m &= m - 1;
                    if (pos < FCAP)
                        fidx[pos * 64 + q] =
                            (unsigned)(cbase + t * 32 + (r & 3) + 8 * (r >> 2) + 4 * hl);
                    ++pos;
                }
            }
        }
    }
    __syncthreads();   // Pm dead; region reused as fdist

    // ---- sweep: exact f32 distances, fully parallel gathers ----
    for (int e = tid; e < FCAP * 64; e += 1024) {
        int j = e >> 6, qq = e & 63;
        int nc = qcnt[qq]; nc = nc > FCAP ? FCAP : nc;
        if (j < nc) {
            float4 Qf = pb[(blockIdx.x << 6) + qq];
            fdist[e] = dist2(Qf, pb[fidx[e]]);
        }
    }
    __syncthreads();

    // ---- final: lexicographic (d asc, idx asc) top-16; overflow fallback ----
    if (tid < 64) {
        int nqf = (blockIdx.x << 6) + tid;
        float4 Qf = pb[nqf];
        float bd[16]; int bi[16];
#pragma unroll
        for (int j = 0; j < 16; ++j) { bd[j] = __builtin_inff(); bi[j] = 0; }
        int cnt = qcnt[tid];
        if (cnt <= FCAP) {
            for (int j = 0; j < cnt; ++j) {
                float x  = fdist[j * 64 + tid];
                int   xi = (int)fidx[j * 64 + tid];
                if (x < bd[15] || (x == bd[15] && xi < bi[15])) {
#pragma unroll
                    for (int t = 0; t < 16; ++t) {
                        bool cc = (x < bd[t]) || (x == bd[t] && xi < bi[t]);
                        float nd = cc ? x  : bd[t];
                        int   ni = cc ? xi : bi[t];
                        float od = cc ? bd[t] : x;
                        int   oi = cc ? bi[t] : xi;
                        bd[t] = nd; bi[t] = ni; x = od; xi = oi;
                    }
                }
            }
        } else {
            // safety fallback: exact brute-force scan (P ~ 1e-10, never expected)
            for (int m = 0; m < NPTS; ++m) {
                float x = dist2(Qf, pb[m]);
                int  xi = m;
                if (x < bd[15] || (x == bd[15] && xi < bi[15])) {
#pragma unroll
                    for (int t = 0; t < 16; ++t) {
                        bool cc = (x < bd[t]) || (x == bd[t] && xi < bi[t]);
                        float nd = cc ? x  : bd[t];
                        int   ni = cc ? xi : bi[t];
                        float od = cc ? bd[t] : x;
                        int   oi = cc ? bi[t] : xi;
                        bd[t] = nd; bi[t] = ni; x = od; xi = oi;
                    }
                }
            }
        }
        int* op = idxout + ((size_t)b * NPTS + nqf) * KNN;
#pragma unroll
        for (int j = 0; j < 16; ++j) op[j] = bi[j];
    }
}

// ---------------------------------------------------------------------------
// Kernel B: fully-register MFMA MLP (unchanged from rounds 4-14).
// ---------------------------------------------------------------------------
__global__ __launch_bounds__(256, 2) void mlp_kernel(
    const float4* __restrict__ pts4, const int* __restrict__ idxin,
    const float* __restrict__ W0, const float* __restrict__ b0,
    const float* __restrict__ W1, const float* __restrict__ b1,
    const float* __restrict__ W2, const float* __restrict__ b2,
    float* __restrict__ out) {

    int tid  = threadIdx.x;
    int wave = tid >> 6, lane = tid & 63;
    int g = lane >> 4, i = lane & 15;

    h2 w0x[8], w0y[8], w0z[8], w0b[8];
#pragma unroll
    for (int s = 0; s < 2; ++s)
#pragma unroll
        for (int v = 0; v < 4; ++v) {
            int c0 = 32 * s + 8 * g + 2 * v;
            w0x[s * 4 + v] = pk2(W0[c0 * 3 + 0], W0[c0 * 3 + 3]);
            w0y[s * 4 + v] = pk2(W0[c0 * 3 + 1], W0[c0 * 3 + 4]);
            w0z[s * 4 + v] = pk2(W0[c0 * 3 + 2], W0[c0 * 3 + 5]);
            w0b[s * 4 + v] = pk2(b0[c0], b0[c0 + 1]);
        }
    h2 b1p[8];
#pragma unroll
    for (int s = 0; s < 2; ++s)
#pragma unroll
        for (int v = 0; v < 4; ++v) {
            int c0 = 32 * s + 16 * (v >> 1) + 4 * g + 2 * (v & 1);
            b1p[s * 4 + v] = pk2(b1[c0], b1[c0 + 1]);
        }
    h8 wf1[4][2];
#pragma unroll
    for (int t = 0; t < 4; ++t)
#pragma unroll
        for (int s = 0; s < 2; ++s) {
            const float* p = W1 + (16 * t + i) * 64 + 32 * s + 8 * g;
            h8 f;
#pragma unroll
            for (int j = 0; j < 8; ++j) f[j] = (_Float16)p[j];
            wf1[t][s] = f;
        }
    h8 wf2[8][2];
#pragma unroll
    for (int t = 0; t < 8; ++t)
#pragma unroll
        for (int s = 0; s < 2; ++s) {
            const float* p = W2 + (16 * t + i) * 64;
            h8 f;
#pragma unroll
            for (int j = 0; j < 8; ++j) {
                int vc = 32 * s + 16 * (j >> 2) + 4 * g + (j & 3);
                f[j] = (_Float16)p[vc];
            }
            wf2[t][s] = f;
        }

    int gw = blockIdx.x * 4 + wave;
    int b  = gw >> 8;
    int n0 = (gw & 255) * 16;

    const float4* pb = pts4 + (size_t)b * NPTS;
    float4 q = pb[n0 + i];
    const int* ip = idxin + ((size_t)b * NPTS + n0 + i) * KNN;

    float mx[8][4];
#pragma unroll
    for (int t = 0; t < 8; ++t)
#pragma unroll
        for (int r = 0; r < 4; ++r) mx[t][r] = -3.4e38f;

    for (int it = 0; it < KNN; ++it) {
        int mi = ip[it];
        float4 p = pb[mi];
        float rx = p.x - q.x, ry = p.y - q.y, rz = p.z - q.z;
        h2 rxx = pk2(rx, rx), ryy = pk2(ry, ry), rzz = pk2(rz, rz);

        h8 h0f[2];
#pragma unroll
        for (int s = 0; s < 2; ++s)
#pragma unroll
            for (int v = 0; v < 4; ++v) {
                h2 hh = __builtin_elementwise_fma(w0z[s * 4 + v], rzz,
                         __builtin_elementwise_fma(w0y[s * 4 + v], ryy,
                          __builtin_elementwise_fma(w0x[s * 4 + v], rxx, w0b[s * 4 + v])));
                hh = __builtin_elementwise_max(hh, (h2)(_Float16)0.0f);
                h0f[s][2 * v]     = hh.x;
                h0f[s][2 * v + 1] = hh.y;
            }

        f4 d1[4];
#pragma unroll
        for (int t = 0; t < 4; ++t) {
            d1[t] = (f4)0.0f;
#pragma unroll
            for (int s = 0; s < 2; ++s)
                d1[t] = __builtin_amdgcn_mfma_f32_16x16x32_f16(wf1[t][s], h0f[s], d1[t], 0, 0, 0);
        }

        h8 h1f[2];
#pragma unroll
        for (int s = 0; s < 2; ++s)
#pragma unroll
            for (int v = 0; v < 4; ++v) {
                int t = 2 * s + (v >> 1), r0 = 2 * (v & 1);
                h2 w = pk2(d1[t][r0], d1[t][r0 + 1]);
                w = w + b1p[s * 4 + v];
                w = __builtin_elementwise_max(w, (h2)(_Float16)0.0f);
                h1f[s][2 * v]     = w.x;
                h1f[s][2 * v + 1] = w.y;
            }

#pragma unroll
        for (int t = 0; t < 8; ++t) {
            f4 d2 = (f4)0.0f;
#pragma unroll
            for (int s = 0; s < 2; ++s)
                d2 = __builtin_amdgcn_mfma_f32_16x16x32_f16(wf2[t][s], h1f[s], d2, 0, 0, 0);
#pragma unroll
            for (int r = 0; r < 4; ++r) mx[t][r] = fmaxf(mx[t][r], d2[r]);
        }
    }

    size_t ob = (size_t)b * 128 * NPTS + n0 + i;
#pragma unroll
    for (int t = 0; t < 8; ++t)
#pragma unroll
        for (int r = 0; r < 4; ++r) {
            int chn = 16 * t + 4 * g + r;
            float v = fmaxf(mx[t][r] + b2[chn], 0.0f);
            out[ob + (size_t)chn * NPTS] = v;
        }
}

// ---------------------------------------------------------------------------
extern "C" void kernel_launch(void* const* d_in, const int* in_sizes, int n_in,
                              void* d_out, int out_size, void* d_ws, size_t ws_size,
                              hipStream_t stream) {
    (void)in_sizes; (void)n_in; (void)out_size; (void)ws_size;
    const float* xyz = (const float*)d_in[0];
    const float* W0  = (const float*)d_in[1];
    const float* b0  = (const float*)d_in[2];
    const float* W1  = (const float*)d_in[3];
    const float* b1  = (const float*)d_in[4];
    const float* W2  = (const float*)d_in[5];
    const float* b2  = (const float*)d_in[6];
    float* out = (float*)d_out;

    char* ws = (char*)d_ws;
    float4* pts4 = (float4*)ws;                                     // 512 KB
    int*    idxb = (int*)(ws + (size_t)NB * NPTS * sizeof(float4)); // 2 MB

    prep_kernel<<<dim3(NB * NPTS / 256), dim3(256), 0, stream>>>(xyz, pts4);
    knn_kernel<<<dim3(NPTS / 64, NB), dim3(1024), 0, stream>>>(pts4, idxb);
    mlp_kernel<<<dim3(512), dim3(256), 0, stream>>>(
        pts4, idxb, W0, b0, W1, b1, W2, b2, out);
}

// Round 16
// 97.123 us; speedup vs baseline: 1.1074x; 1.1074x over previous
//
#include <hip/hip_runtime.h>
#include <cstddef>

#define NB   8
#define NPTS 4096
#define KNN  16
#define FCAP 64    // per-query collected-candidate capacity
#define QB   32    // queries per knn block

typedef _Float16 h2 __attribute__((ext_vector_type(2)));
typedef _Float16 h8 __attribute__((ext_vector_type(8)));
typedef float    f4 __attribute__((ext_vector_type(4)));
typedef float    f16f __attribute__((ext_vector_type(16)));

static __device__ __forceinline__ h2 pk2(float a, float b) {
    return __builtin_bit_cast(h2, __builtin_amdgcn_cvt_pkrtz(a, b));
}
static __device__ __forceinline__ unsigned bch(h2 v) {
    return __builtin_bit_cast(unsigned, v);
}

#if __has_builtin(__builtin_amdgcn_fmed3f)
static __device__ __forceinline__ float MED3(float a, float b, float c) {
    return __builtin_amdgcn_fmed3f(a, b, c);
}
#else
static __device__ __forceinline__ float MED3(float a, float b, float c) {
    return fmaxf(fminf(a, b), fminf(fmaxf(a, b), c));
}
#endif

// Exact f32 distance (sq-form). Same fmaf nesting as prep's sq -> self-dist
// is exactly 0. Used ONLY for the exact candidate distances.
static __device__ __forceinline__ float dist2(float4 Q, float4 p) {
    float dot = fmaf(Q.z, p.z, fmaf(Q.y, p.y, Q.x * p.x));
    return fmaf(-2.0f, dot, Q.w + p.w);
}

// ---------------------------------------------------------------------------
// Kernel P: one block per batch. Packs pts4 (f32) + pm16 (f16 xh,yh|zh,sh)
// and reduces exact per-batch pmax/smax to global (mx[b] = {pmax,smax}).
// ---------------------------------------------------------------------------
__global__ __launch_bounds__(1024) void prep_kernel(const float* __restrict__ xyz,
                                                    float4* __restrict__ pts4,
                                                    uint2* __restrict__ pm16,
                                                    unsigned* __restrict__ mx) {
    __shared__ float wred[32];
    int b = blockIdx.x, tid = threadIdx.x;
    const float* base = xyz + (size_t)b * 3 * NPTS;
    float lm = 0.0f, ls = 0.0f;
    for (int j = tid; j < NPTS; j += 1024) {
        float x = base[j];
        float y = base[NPTS + j];
        float z = base[2 * NPTS + j];
        float sq = fmaf(z, z, fmaf(y, y, x * x));   // same nesting as dist2's dot
        pts4[(size_t)b * NPTS + j] = make_float4(x, y, z, sq);
        h2 lo = { (_Float16)x, (_Float16)y };
        h2 hi = { (_Float16)z, (_Float16)sq };
        pm16[(size_t)b * NPTS + j] = make_uint2(bch(lo), bch(hi));
        lm = fmaxf(lm, fmaxf(fabsf(x), fmaxf(fabsf(y), fabsf(z))));
        ls = fmaxf(ls, sq);
    }
#pragma unroll
    for (int o = 32; o; o >>= 1) {
        lm = fmaxf(lm, __shfl_xor(lm, o));
        ls = fmaxf(ls, __shfl_xor(ls, o));
    }
    int wave = tid >> 6, lane = tid & 63;
    if (lane == 0) { wred[wave] = lm; wred[16 + wave] = ls; }
    __syncthreads();
    if (tid == 0) {
        float m = wred[0], s = wred[16];
#pragma unroll
        for (int i = 1; i < 16; ++i) { m = fmaxf(m, wred[i]); s = fmaxf(s, wred[16 + i]); }
        mx[b * 2 + 0] = __builtin_bit_cast(unsigned, m);
        mx[b * 2 + 1] = __builtin_bit_cast(unsigned, s);
    }
}

// ---------------------------------------------------------------------------
// Kernel A: exact 16-NN, 32x32x16 MFMA pruning keys. Round-16 restructure:
//  - block = 512 thr (8 waves) x 32 queries; grid (128, NB) = 1024 blocks
//    -> 4 blocks/CU co-resident (32 waves/CU) so one block's serial
//    merge/final overlaps other blocks' scans. Same total MFMA work.
//  - no LDS candidate staging: A-fragments read directly from global pm16
//    (32 KB/batch, L1/L2-resident, coalesced). LDS = 16.5 KB/block.
// Selection math identical to rounds 14/15: dup-trick split keys
// g = p_h.(u_h+u_l)+s_h, min-of-16 + sorted-4 phase 1, per-query tight E,
// mask-compact phase-2 push, parallel exact f32 sweep, lexicographic
// (d,idx) final select == jax.lax.top_k tie-break, brute-force fallback.
// ---------------------------------------------------------------------------
__global__ __launch_bounds__(512, 8) void knn_kernel(const float4* __restrict__ pts4,
                                                     const uint2* __restrict__ pm16,
                                                     const unsigned* __restrict__ mx,
                                                     int* __restrict__ idxout) {
    __shared__ char  sbuf[8192];                      // partials -> fidx (8 KB)
    __shared__ float fdist[FCAP * QB];                // 8 KB
    __shared__ float tauv[QB];
    __shared__ int   qcnt[QB];

    float*    partials = (float*)sbuf;                // [64 slots][QB]
    unsigned* fidx     = (unsigned*)sbuf;             // [FCAP][QB]

    int tid = threadIdx.x;
    int b   = blockIdx.y;
    const float4* pb  = pts4 + (size_t)b * NPTS;
    const uint2*  pmb = pm16 + (size_t)b * NPTS;

    int wave = tid >> 6, lane = tid & 63;
    int c   = wave;               // candidate chunk 0..7 (512 cands)
    int col = lane & 31;          // A-row / B-col / D-col
    int hl  = lane >> 5;          // lane half (k-slot group / D row group)
    int q   = col;                // query 0..31
    int nq  = blockIdx.x * QB + q;
    int cbase = c * 512;

    float4 qf = pb[nq];
    float uxf = -2.0f * qf.x, uyf = -2.0f * qf.y, uzf = -2.0f * qf.z;  // exact
    _Float16 uxh = (_Float16)uxf, uyh = (_Float16)uyf, uzh = (_Float16)uzf;
    _Float16 uxl = (_Float16)(uxf - (float)uxh);
    _Float16 uyl = (_Float16)(uyf - (float)uyh);
    _Float16 uzl = (_Float16)(uzf - (float)uzh);
    uint4 bu = {0u, 0u, 0u, 0u};
    if (hl == 0) {
        h2 b01 = {uxh, uyh}, b23 = {uzh, (_Float16)1.0f};
        h2 b45 = {uxl, uyl}, b67 = {uzl, (_Float16)0.0f};
        bu.x = bch(b01); bu.y = bch(b23); bu.z = bch(b45); bu.w = bch(b67);
    }
    h8 bq = __builtin_bit_cast(h8, bu);

    // ---- phase 1: 16 MFMA tiles (32 cands x 32 q), min16 + sorted-4 ----
    {
        float c0 = __builtin_inff(), c1 = c0, c2 = c0, c3 = c0;
#pragma unroll 2
        for (int t = 0; t < 16; ++t) {
            uint4 au = {0u, 0u, 0u, 0u};
            if (hl == 0) {
                uint2 pd = pmb[cbase + t * 32 + col];
                au.x = pd.x; au.y = pd.y; au.z = pd.x; au.w = pd.y;  // k0-3 & k4-7
            }
            f16f d = __builtin_amdgcn_mfma_f32_32x32x16_f16(
                __builtin_bit_cast(h8, au), bq, (f16f)0.0f, 0, 0, 0);
            float a0 = fminf(d[0], d[1]),   a1 = fminf(d[2], d[3]);
            float a2 = fminf(d[4], d[5]),   a3 = fminf(d[6], d[7]);
            float a4 = fminf(d[8], d[9]),   a5 = fminf(d[10], d[11]);
            float a6 = fminf(d[12], d[13]), a7 = fminf(d[14], d[15]);
            float b0 = fminf(a0, a1), b1 = fminf(a2, a3);
            float b2 = fminf(a4, a5), b3 = fminf(a6, a7);
            float rmin = fminf(fminf(b0, b1), fminf(b2, b3));
            float p0 = c0, p1 = c1, p2 = c2;
            c0 = fminf(p0, rmin);
            c1 = MED3(rmin, p0, c1);
            c2 = MED3(rmin, p1, c2);
            c3 = MED3(rmin, p2, c3);
        }
        int sb = (c * 2 + hl) * 4;
        partials[(sb + 0) * QB + q] = c0;
        partials[(sb + 1) * QB + q] = c1;
        partials[(sb + 2) * QB + q] = c2;
        partials[(sb + 3) * QB + q] = c3;
    }
    __syncthreads();

    // ---- merge level 1 (IN PLACE): 4 mergers/query x 16 slots -> sorted-16 ----
    if (tid < 4 * QB) {
        int qq = tid & (QB - 1), k = tid >> 5;
        float mb[16];
#pragma unroll
        for (int j = 0; j < 16; ++j) mb[j] = __builtin_inff();
        for (int s = 0; s < 16; ++s) {
            float v = partials[(k * 16 + s) * QB + qq];
            float prev = mb[0];
            mb[0] = fminf(mb[0], v);
#pragma unroll
            for (int i = 1; i < 16; ++i) {
                float cur = mb[i];
                mb[i] = MED3(v, prev, cur);
                prev = cur;
            }
        }
#pragma unroll
        for (int j = 0; j < 16; ++j) partials[(k * 16 + j) * QB + qq] = mb[j];
    }
    __syncthreads();

    // ---- merge level 2: 16th of 4 sorted lists; per-query tight bound ----
    if (tid < QB) {
        float mb[16];
#pragma unroll
        for (int j = 0; j < 16; ++j) mb[j] = __builtin_inff();
        for (int k = 0; k < 4; ++k) {
            for (int j = 0; j < 16; ++j) {
                float v = partials[(k * 16 + j) * QB + tid];
                if (v >= mb[15]) break;             // ascending list
                float prev = mb[0];
                mb[0] = fminf(mb[0], v);
#pragma unroll
                for (int i = 1; i < 16; ++i) {
                    float cur = mb[i];
                    mb[i] = MED3(v, prev, cur);
                    prev = cur;
                }
            }
        }
        float4 q2 = pb[blockIdx.x * QB + tid];
        float sumq = fabsf(q2.x) + fabsf(q2.y) + fabsf(q2.z);
        float qn   = sqrtf(q2.w);                   // |q| (q2.w = |q|^2 >= 0)
        float pmax = __builtin_bit_cast(float, mx[b * 2 + 0]);
        float smax = __builtin_bit_cast(float, mx[b * 2 + 1]);
        const float r11c = 4.8828125e-4f;           // 2^-11
        float tau = mb[15];
        float E0  = smax * r11c + 2.0f * sumq * pmax * r11c + 1.0e-3f;
        float rad2 = fmaxf(tau + 2.0f * E0 + q2.w, 0.0f);
        float R   = qn + sqrtf(rad2);
        float Eq  = (R * R + 2.0f * sumq * R) * r11c + 6.0e-4f;
        Eq = fminf(Eq, E0);
        tauv[tid] = tau + 2.0f * Eq;
        qcnt[tid] = 0;
    }
    __syncthreads();   // partials dead; sbuf reused as fidx

    // ---- phase 2: same MFMA (deterministic), mask-compact pushes ----
    {
        float tc = tauv[q];
#pragma unroll 1
        for (int t = 0; t < 16; ++t) {
            uint4 au = {0u, 0u, 0u, 0u};
            if (hl == 0) {
                uint2 pd = pmb[cbase + t * 32 + col];
                au.x = pd.x; au.y = pd.y; au.z = pd.x; au.w = pd.y;
            }
            f16f d = __builtin_amdgcn_mfma_f32_32x32x16_f16(
                __builtin_bit_cast(h8, au), bq, (f16f)0.0f, 0, 0, 0);
            unsigned m = 0u;
#pragma unroll
            for (int r = 0; r < 16; ++r) m |= (d[r] <= tc) ? (1u << r) : 0u;
            if (m) {
                int pos = atomicAdd(&qcnt[q], __popc(m));
                while (m) {
                    int r = __ffs(m) - 1;
                    m &= m - 1;
                    if (pos < FCAP)
                        fidx[pos * QB + q] =
                            (unsigned)(cbase + t * 32 + (r & 3) + 8 * (r >> 2) + 4 * hl);
                    ++pos;
                }
            }
        }
    }
    __syncthreads();

    // ---- sweep: exact f32 distances, fully parallel gathers ----
    for (int e = tid; e < FCAP * QB; e += 512) {
        int j = e >> 5, qq = e & (QB - 1);
        int nc = qcnt[qq]; nc = nc > FCAP ? FCAP : nc;
        if (j < nc) {
            float4 Qf = pb[blockIdx.x * QB + qq];
            fdist[e] = dist2(Qf, pb[fidx[e]]);
        }
    }
    __syncthreads();

    // ---- final: lexicographic (d asc, idx asc) top-16; overflow fallback ----
    if (tid < QB) {
        int nqf = blockIdx.x * QB + tid;
        float4 Qf = pb[nqf];
        float bd[16]; int bi[16];
#pragma unroll
        for (int j = 0; j < 16; ++j) { bd[j] = __builtin_inff(); bi[j] = 0; }
        int cnt = qcnt[tid];
        if (cnt <= FCAP) {
            for (int j = 0; j < cnt; ++j) {
                float x  = fdist[j * QB + tid];
                int   xi = (int)fidx[j * QB + tid];
                if (x < bd[15] || (x == bd[15] && xi < bi[15])) {
#pragma unroll
                    for (int t = 0; t < 16; ++t) {
                        bool cc = (x < bd[t]) || (x == bd[t] && xi < bi[t]);
                        float nd = cc ? x  : bd[t];
                        int   ni = cc ? xi : bi[t];
                        float od = cc ? bd[t] : x;
                        int   oi = cc ? bi[t] : xi;
                        bd[t] = nd; bi[t] = ni; x = od; xi = oi;
                    }
                }
            }
        } else {
            // safety fallback: exact brute-force scan (P ~ 1e-10, never expected)
            for (int m = 0; m < NPTS; ++m) {
                float x = dist2(Qf, pb[m]);
                int  xi = m;
                if (x < bd[15] || (x == bd[15] && xi < bi[15])) {
#pragma unroll
                    for (int t = 0; t < 16; ++t) {
                        bool cc = (x < bd[t]) || (x == bd[t] && xi < bi[t]);
                        float nd = cc ? x  : bd[t];
                        int   ni = cc ? xi : bi[t];
                        float od = cc ? bd[t] : x;
                        int   oi = cc ? bi[t] : xi;
                        bd[t] = nd; bi[t] = ni; x = od; xi = oi;
                    }
                }
            }
        }
        int* op = idxout + ((size_t)b * NPTS + nqf) * KNN;
#pragma unroll
        for (int j = 0; j < 16; ++j) op[j] = bi[j];
    }
}

// ---------------------------------------------------------------------------
// Kernel B: fully-register MFMA MLP (unchanged from rounds 4-15).
// ---------------------------------------------------------------------------
__global__ __launch_bounds__(256, 2) void mlp_kernel(
    const float4* __restrict__ pts4, const int* __restrict__ idxin,
    const float* __restrict__ W0, const float* __restrict__ b0,
    const float* __restrict__ W1, const float* __restrict__ b1,
    const float* __restrict__ W2, const float* __restrict__ b2,
    float* __restrict__ out) {

    int tid  = threadIdx.x;
    int wave = tid >> 6, lane = tid & 63;
    int g = lane >> 4, i = lane & 15;

    h2 w0x[8], w0y[8], w0z[8], w0b[8];
#pragma unroll
    for (int s = 0; s < 2; ++s)
#pragma unroll
        for (int v = 0; v < 4; ++v) {
            int c0 = 32 * s + 8 * g + 2 * v;
            w0x[s * 4 + v] = pk2(W0[c0 * 3 + 0], W0[c0 * 3 + 3]);
            w0y[s * 4 + v] = pk2(W0[c0 * 3 + 1], W0[c0 * 3 + 4]);
            w0z[s * 4 + v] = pk2(W0[c0 * 3 + 2], W0[c0 * 3 + 5]);
            w0b[s * 4 + v] = pk2(b0[c0], b0[c0 + 1]);
        }
    h2 b1p[8];
#pragma unroll
    for (int s = 0; s < 2; ++s)
#pragma unroll
        for (int v = 0; v < 4; ++v) {
            int c0 = 32 * s + 16 * (v >> 1) + 4 * g + 2 * (v & 1);
            b1p[s * 4 + v] = pk2(b1[c0], b1[c0 + 1]);
        }
    h8 wf1[4][2];
#pragma unroll
    for (int t = 0; t < 4; ++t)
#pragma unroll
        for (int s = 0; s < 2; ++s) {
            const float* p = W1 + (16 * t + i) * 64 + 32 * s + 8 * g;
            h8 f;
#pragma unroll
            for (int j = 0; j < 8; ++j) f[j] = (_Float16)p[j];
            wf1[t][s] = f;
        }
    h8 wf2[8][2];
#pragma unroll
    for (int t = 0; t < 8; ++t)
#pragma unroll
        for (int s = 0; s < 2; ++s) {
            const float* p = W2 + (16 * t + i) * 64;
            h8 f;
#pragma unroll
            for (int j = 0; j < 8; ++j) {
                int vc = 32 * s + 16 * (j >> 2) + 4 * g + (j & 3);
                f[j] = (_Float16)p[vc];
            }
            wf2[t][s] = f;
        }

    int gw = blockIdx.x * 4 + wave;
    int b  = gw >> 8;
    int n0 = (gw & 255) * 16;

    const float4* pb = pts4 + (size_t)b * NPTS;
    float4 q = pb[n0 + i];
    const int* ip = idxin + ((size_t)b * NPTS + n0 + i) * KNN;

    float mx[8][4];
#pragma unroll
    for (int t = 0; t < 8; ++t)
#pragma unroll
        for (int r = 0; r < 4; ++r) mx[t][r] = -3.4e38f;

    for (int it = 0; it < KNN; ++it) {
        int mi = ip[it];
        float4 p = pb[mi];
        float rx = p.x - q.x, ry = p.y - q.y, rz = p.z - q.z;
        h2 rxx = pk2(rx, rx), ryy = pk2(ry, ry), rzz = pk2(rz, rz);

        h8 h0f[2];
#pragma unroll
        for (int s = 0; s < 2; ++s)
#pragma unroll
            for (int v = 0; v < 4; ++v) {
                h2 hh = __builtin_elementwise_fma(w0z[s * 4 + v], rzz,
                         __builtin_elementwise_fma(w0y[s * 4 + v], ryy,
                          __builtin_elementwise_fma(w0x[s * 4 + v], rxx, w0b[s * 4 + v])));
                hh = __builtin_elementwise_max(hh, (h2)(_Float16)0.0f);
                h0f[s][2 * v]     = hh.x;
                h0f[s][2 * v + 1] = hh.y;
            }

        f4 d1[4];
#pragma unroll
        for (int t = 0; t < 4; ++t) {
            d1[t] = (f4)0.0f;
#pragma unroll
            for (int s = 0; s < 2; ++s)
                d1[t] = __builtin_amdgcn_mfma_f32_16x16x32_f16(wf1[t][s], h0f[s], d1[t], 0, 0, 0);
        }

        h8 h1f[2];
#pragma unroll
        for (int s = 0; s < 2; ++s)
#pragma unroll
            for (int v = 0; v < 4; ++v) {
                int t = 2 * s + (v >> 1), r0 = 2 * (v & 1);
                h2 w = pk2(d1[t][r0], d1[t][r0 + 1]);
                w = w + b1p[s * 4 + v];
                w = __builtin_elementwise_max(w, (h2)(_Float16)0.0f);
                h1f[s][2 * v]     = w.x;
                h1f[s][2 * v + 1] = w.y;
            }

#pragma unroll
        for (int t = 0; t < 8; ++t) {
            f4 d2 = (f4)0.0f;
#pragma unroll
            for (int s = 0; s < 2; ++s)
                d2 = __builtin_amdgcn_mfma_f32_16x16x32_f16(wf2[t][s], h1f[s], d2, 0, 0, 0);
#pragma unroll
            for (int r = 0; r < 4; ++r) mx[t][r] = fmaxf(mx[t][r], d2[r]);
        }
    }

    size_t ob = (size_t)b * 128 * NPTS + n0 + i;
#pragma unroll
    for (int t = 0; t < 8; ++t)
#pragma unroll
        for (int r = 0; r < 4; ++r) {
            int chn = 16 * t + 4 * g + r;
            float v = fmaxf(mx[t][r] + b2[chn], 0.0f);
            out[ob + (size_t)chn * NPTS] = v;
        }
}

// ---------------------------------------------------------------------------
extern "C" void kernel_launch(void* const* d_in, const int* in_sizes, int n_in,
                              void* d_out, int out_size, void* d_ws, size_t ws_size,
                              hipStream_t stream) {
    (void)in_sizes; (void)n_in; (void)out_size; (void)ws_size;
    const float* xyz = (const float*)d_in[0];
    const float* W0  = (const float*)d_in[1];
    const float* b0  = (const float*)d_in[2];
    const float* W1  = (const float*)d_in[3];
    const float* b1  = (const float*)d_in[4];
    const float* W2  = (const float*)d_in[5];
    const float* b2  = (const float*)d_in[6];
    float* out = (float*)d_out;

    char* ws = (char*)d_ws;
    float4*   pts4 = (float4*)ws;                                   // 512 KB
    int*      idxb = (int*)(ws + (512 << 10));                      // 2 MB
    uint2*    pm16 = (uint2*)(ws + (512 << 10) + (2 << 20));        // 256 KB
    unsigned* mxb  = (unsigned*)(ws + (512 << 10) + (2 << 20) + (256 << 10)); // 64 B

    prep_kernel<<<dim3(NB), dim3(1024), 0, stream>>>(xyz, pts4, pm16, mxb);
    knn_kernel<<<dim3(NPTS / QB, NB), dim3(512), 0, stream>>>(pts4, pm16, mxb, idxb);
    mlp_kernel<<<dim3(512), dim3(256), 0, stream>>>(
        pts4, idxb, W0, b0, W1, b1, W2, b2, out);
}

// Round 17
// 95.728 us; speedup vs baseline: 1.1236x; 1.0146x over previous
//
#include <hip/hip_runtime.h>
#include <cstddef>

#define NB   8
#define NPTS 4096
#define KNN  16
#define FCAP 64    // per-query collected-candidate capacity
#define QB   32    // queries per knn block

typedef _Float16 h2 __attribute__((ext_vector_type(2)));
typedef _Float16 h8 __attribute__((ext_vector_type(8)));
typedef float    f4 __attribute__((ext_vector_type(4)));
typedef float    f16f __attribute__((ext_vector_type(16)));

static __device__ __forceinline__ h2 pk2(float a, float b) {
    return __builtin_bit_cast(h2, __builtin_amdgcn_cvt_pkrtz(a, b));
}
static __device__ __forceinline__ unsigned bch(h2 v) {
    return __builtin_bit_cast(unsigned, v);
}

#if __has_builtin(__builtin_amdgcn_fmed3f)
static __device__ __forceinline__ float MED3(float a, float b, float c) {
    return __builtin_amdgcn_fmed3f(a, b, c);
}
#else
static __device__ __forceinline__ float MED3(float a, float b, float c) {
    return fmaxf(fminf(a, b), fminf(fmaxf(a, b), c));
}
#endif
// nested-min triple -> clang fuses to v_min3_f32
static __device__ __forceinline__ float MIN3(float a, float b, float c) {
    return fminf(fminf(a, b), c);
}

// Exact f32 distance (sq-form). Same fmaf nesting as prep's sq -> self-dist
// is exactly 0. Used ONLY for the exact candidate distances.
static __device__ __forceinline__ float dist2(float4 Q, float4 p) {
    float dot = fmaf(Q.z, p.z, fmaf(Q.y, p.y, Q.x * p.x));
    return fmaf(-2.0f, dot, Q.w + p.w);
}

// ---------------------------------------------------------------------------
// Kernel P: one block per batch. Packs pts4 (f32) + pm16 (f16 xh,yh|zh,sh)
// and reduces exact per-batch pmax/smax to global (mx[b] = {pmax,smax}).
// ---------------------------------------------------------------------------
__global__ __launch_bounds__(1024) void prep_kernel(const float* __restrict__ xyz,
                                                    float4* __restrict__ pts4,
                                                    uint2* __restrict__ pm16,
                                                    unsigned* __restrict__ mx) {
    __shared__ float wred[32];
    int b = blockIdx.x, tid = threadIdx.x;
    const float* base = xyz + (size_t)b * 3 * NPTS;
    float lm = 0.0f, ls = 0.0f;
    for (int j = tid; j < NPTS; j += 1024) {
        float x = base[j];
        float y = base[NPTS + j];
        float z = base[2 * NPTS + j];
        float sq = fmaf(z, z, fmaf(y, y, x * x));   // same nesting as dist2's dot
        pts4[(size_t)b * NPTS + j] = make_float4(x, y, z, sq);
        h2 lo = { (_Float16)x, (_Float16)y };
        h2 hi = { (_Float16)z, (_Float16)sq };
        pm16[(size_t)b * NPTS + j] = make_uint2(bch(lo), bch(hi));
        lm = fmaxf(lm, fmaxf(fabsf(x), fmaxf(fabsf(y), fabsf(z))));
        ls = fmaxf(ls, sq);
    }
#pragma unroll
    for (int o = 32; o; o >>= 1) {
        lm = fmaxf(lm, __shfl_xor(lm, o));
        ls = fmaxf(ls, __shfl_xor(ls, o));
    }
    int wave = tid >> 6, lane = tid & 63;
    if (lane == 0) { wred[wave] = lm; wred[16 + wave] = ls; }
    __syncthreads();
    if (tid == 0) {
        float m = wred[0], s = wred[16];
#pragma unroll
        for (int i = 1; i < 16; ++i) { m = fmaxf(m, wred[i]); s = fmaxf(s, wred[16 + i]); }
        mx[b * 2 + 0] = __builtin_bit_cast(unsigned, m);
        mx[b * 2 + 1] = __builtin_bit_cast(unsigned, s);
    }
}

// ---------------------------------------------------------------------------
// Kernel A: exact 16-NN, 32x32x16 MFMA pruning keys. Round-17 restructure:
//  - block = 256 thr (4 waves) x 32 queries; each wave owns 1024 cands as
//    TWO interleaved streams (dual sorted-4 chains, 2 loads + 2 MFMAs in
//    flight) -> 64 partials/query, identical tau_hat quality to round 16.
//    8 potential blocks/CU so serial merge/final overlap other blocks' scans.
//  - min-of-16 via v_min3_f32 triples (8 ops, was 15).
// Selection math identical: dup-trick split keys g = p_h.(u_h+u_l)+s_h,
// per-query tight E, mask-compact phase-2 push, parallel exact f32 sweep,
// lexicographic (d,idx) final select == jax.lax.top_k tie-break, fallback.
// ---------------------------------------------------------------------------
__global__ __launch_bounds__(256, 6) void knn_kernel(const float4* __restrict__ pts4,
                                                     const uint2* __restrict__ pm16,
                                                     const unsigned* __restrict__ mx,
                                                     int* __restrict__ idxout) {
    __shared__ char  sbuf[8192];                      // partials -> fidx (8 KB)
    __shared__ float fdist[FCAP * QB];                // 8 KB
    __shared__ float tauv[QB];
    __shared__ int   qcnt[QB];

    float*    partials = (float*)sbuf;                // [64 slots][QB]
    unsigned* fidx     = (unsigned*)sbuf;             // [FCAP][QB]

    int tid = threadIdx.x;
    int b   = blockIdx.y;
    const float4* pb  = pts4 + (size_t)b * NPTS;
    const uint2*  pmb = pm16 + (size_t)b * NPTS;

    int wave = tid >> 6, lane = tid & 63;
    int col = lane & 31;          // A-row / B-col / D-col
    int hl  = lane >> 5;          // lane half (k-slot group / D row group)
    int q   = col;                // query 0..31
    int nq  = blockIdx.x * QB + q;
    int cb  = wave * 1024;        // this wave's candidate base (2 chunks)

    float4 qf = pb[nq];
    float uxf = -2.0f * qf.x, uyf = -2.0f * qf.y, uzf = -2.0f * qf.z;  // exact
    _Float16 uxh = (_Float16)uxf, uyh = (_Float16)uyf, uzh = (_Float16)uzf;
    _Float16 uxl = (_Float16)(uxf - (float)uxh);
    _Float16 uyl = (_Float16)(uyf - (float)uyh);
    _Float16 uzl = (_Float16)(uzf - (float)uzh);
    uint4 bu = {0u, 0u, 0u, 0u};
    if (hl == 0) {
        h2 b01 = {uxh, uyh}, b23 = {uzh, (_Float16)1.0f};
        h2 b45 = {uxl, uyl}, b67 = {uzl, (_Float16)0.0f};
        bu.x = bch(b01); bu.y = bch(b23); bu.z = bch(b45); bu.w = bch(b67);
    }
    h8 bq = __builtin_bit_cast(h8, bu);

    // ---- phase 1: 2x16 MFMA tiles, dual streams, min3-tree + sorted-4 ----
    {
        float a0 = __builtin_inff(), a1 = a0, a2 = a0, a3 = a0;   // stream A
        float c0 = a0, c1 = a0, c2 = a0, c3 = a0;                 // stream B
#pragma unroll 1
        for (int t = 0; t < 16; ++t) {
            uint4 auA = {0u, 0u, 0u, 0u}, auB = {0u, 0u, 0u, 0u};
            if (hl == 0) {
                uint2 pdA = pmb[cb + t * 32 + col];
                uint2 pdB = pmb[cb + 512 + t * 32 + col];
                auA.x = pdA.x; auA.y = pdA.y; auA.z = pdA.x; auA.w = pdA.y;
                auB.x = pdB.x; auB.y = pdB.y; auB.z = pdB.x; auB.w = pdB.y;
            }
            f16f dA = __builtin_amdgcn_mfma_f32_32x32x16_f16(
                __builtin_bit_cast(h8, auA), bq, (f16f)0.0f, 0, 0, 0);
            f16f dB = __builtin_amdgcn_mfma_f32_32x32x16_f16(
                __builtin_bit_cast(h8, auB), bq, (f16f)0.0f, 0, 0, 0);
            {
                float v0 = MIN3(dA[0], dA[1], dA[2]);
                float v1 = MIN3(dA[3], dA[4], dA[5]);
                float v2 = MIN3(dA[6], dA[7], dA[8]);
                float v3 = MIN3(dA[9], dA[10], dA[11]);
                float v4 = MIN3(dA[12], dA[13], dA[14]);
                float w0 = MIN3(v0, v1, v2);
                float w1 = MIN3(v3, v4, dA[15]);
                float rmin = fminf(w0, w1);
                float p0 = a0, p1 = a1, p2 = a2;
                a0 = fminf(p0, rmin);
                a1 = MED3(rmin, p0, a1);
                a2 = MED3(rmin, p1, a2);
                a3 = MED3(rmin, p2, a3);
            }
            {
                float v0 = MIN3(dB[0], dB[1], dB[2]);
                float v1 = MIN3(dB[3], dB[4], dB[5]);
                float v2 = MIN3(dB[6], dB[7], dB[8]);
                float v3 = MIN3(dB[9], dB[10], dB[11]);
                float v4 = MIN3(dB[12], dB[13], dB[14]);
                float w0 = MIN3(v0, v1, v2);
                float w1 = MIN3(v3, v4, dB[15]);
                float rmin = fminf(w0, w1);
                float p0 = c0, p1 = c1, p2 = c2;
                c0 = fminf(p0, rmin);
                c1 = MED3(rmin, p0, c1);
                c2 = MED3(rmin, p1, c2);
                c3 = MED3(rmin, p2, c3);
            }
        }
        int g0 = ((wave * 2 + 0) * 2 + hl) * 4;   // stream A slot group
        int g1 = ((wave * 2 + 1) * 2 + hl) * 4;   // stream B slot group
        partials[(g0 + 0) * QB + q] = a0;
        partials[(g0 + 1) * QB + q] = a1;
        partials[(g0 + 2) * QB + q] = a2;
        partials[(g0 + 3) * QB + q] = a3;
        partials[(g1 + 0) * QB + q] = c0;
        partials[(g1 + 1) * QB + q] = c1;
        partials[(g1 + 2) * QB + q] = c2;
        partials[(g1 + 3) * QB + q] = c3;
    }
    __syncthreads();

    // ---- merge level 1 (IN PLACE): 4 mergers/query x 16 slots -> sorted-16 ----
    if (tid < 4 * QB) {
        int qq = tid & (QB - 1), k = tid >> 5;
        float mb[16];
#pragma unroll
        for (int j = 0; j < 16; ++j) mb[j] = __builtin_inff();
        for (int s = 0; s < 16; ++s) {
            float v = partials[(k * 16 + s) * QB + qq];
            float prev = mb[0];
            mb[0] = fminf(mb[0], v);
#pragma unroll
            for (int i = 1; i < 16; ++i) {
                float cur = mb[i];
                mb[i] = MED3(v, prev, cur);
                prev = cur;
            }
        }
#pragma unroll
        for (int j = 0; j < 16; ++j) partials[(k * 16 + j) * QB + qq] = mb[j];
    }
    __syncthreads();

    // ---- merge level 2: 16th of 4 sorted lists; per-query tight bound ----
    if (tid < QB) {
        float mb[16];
#pragma unroll
        for (int j = 0; j < 16; ++j) mb[j] = __builtin_inff();
        for (int k = 0; k < 4; ++k) {
            for (int j = 0; j < 16; ++j) {
                float v = partials[(k * 16 + j) * QB + tid];
                if (v >= mb[15]) break;             // ascending list
                float prev = mb[0];
                mb[0] = fminf(mb[0], v);
#pragma unroll
                for (int i = 1; i < 16; ++i) {
                    float cur = mb[i];
                    mb[i] = MED3(v, prev, cur);
                    prev = cur;
                }
            }
        }
        float4 q2 = pb[blockIdx.x * QB + tid];
        float sumq = fabsf(q2.x) + fabsf(q2.y) + fabsf(q2.z);
        float qn   = sqrtf(q2.w);                   // |q| (q2.w = |q|^2 >= 0)
        float pmax = __builtin_bit_cast(float, mx[b * 2 + 0]);
        float smax = __builtin_bit_cast(float, mx[b * 2 + 1]);
        const float r11c = 4.8828125e-4f;           // 2^-11
        float tau = mb[15];
        float E0  = smax * r11c + 2.0f * sumq * pmax * r11c + 1.0e-3f;
        float rad2 = fmaxf(tau + 2.0f * E0 + q2.w, 0.0f);
        float R   = qn + sqrtf(rad2);
        float Eq  = (R * R + 2.0f * sumq * R) * r11c + 6.0e-4f;
        Eq = fminf(Eq, E0);
        tauv[tid] = tau + 2.0f * Eq;
        qcnt[tid] = 0;
    }
    __syncthreads();   // partials dead; sbuf reused as fidx

    // ---- phase 2: same MFMA (deterministic), mask-compact pushes ----
    {
        float tc = tauv[q];
#pragma unroll 1
        for (int t = 0; t < 32; ++t) {
            uint4 au = {0u, 0u, 0u, 0u};
            if (hl == 0) {
                uint2 pd = pmb[cb + t * 32 + col];
                au.x = pd.x; au.y = pd.y; au.z = pd.x; au.w = pd.y;
            }
            f16f d = __builtin_amdgcn_mfma_f32_32x32x16_f16(
                __builtin_bit_cast(h8, au), bq, (f16f)0.0f, 0, 0, 0);
            unsigned m = 0u;
#pragma unroll
            for (int r = 0; r < 16; ++r) m |= (d[r] <= tc) ? (1u << r) : 0u;
            if (m) {
                int pos = atomicAdd(&qcnt[q], __popc(m));
                while (m) {
                    int r = __ffs(m) - 1;
                    m &= m - 1;
                    if (pos < FCAP)
                        fidx[pos * QB + q] =
                            (unsigned)(cb + t * 32 + (r & 3) + 8 * (r >> 2) + 4 * hl);
                    ++pos;
                }
            }
        }
    }
    __syncthreads();

    // ---- sweep: exact f32 distances, fully parallel gathers ----
    for (int e = tid; e < FCAP * QB; e += 256) {
        int j = e >> 5, qq = e & (QB - 1);
        int nc = qcnt[qq]; nc = nc > FCAP ? FCAP : nc;
        if (j < nc) {
            float4 Qf = pb[blockIdx.x * QB + qq];
            fdist[e] = dist2(Qf, pb[fidx[e]]);
        }
    }
    __syncthreads();

    // ---- final: lexicographic (d asc, idx asc) top-16; overflow fallback ----
    if (tid < QB) {
        int nqf = blockIdx.x * QB + tid;
        float4 Qf = pb[nqf];
        float bd[16]; int bi[16];
#pragma unroll
        for (int j = 0; j < 16; ++j) { bd[j] = __builtin_inff(); bi[j] = 0; }
        int cnt = qcnt[tid];
        if (cnt <= FCAP) {
            for (int j = 0; j < cnt; ++j) {
                float x  = fdist[j * QB + tid];
                int   xi = (int)fidx[j * QB + tid];
                if (x < bd[15] || (x == bd[15] && xi < bi[15])) {
#pragma unroll
                    for (int t = 0; t < 16; ++t) {
                        bool cc = (x < bd[t]) || (x == bd[t] && xi < bi[t]);
                        float nd = cc ? x  : bd[t];
                        int   ni = cc ? xi : bi[t];
                        float od = cc ? bd[t] : x;
                        int   oi = cc ? bi[t] : xi;
                        bd[t] = nd; bi[t] = ni; x = od; xi = oi;
                    }
                }
            }
        } else {
            // safety fallback: exact brute-force scan (P ~ 1e-10, never expected)
            for (int m = 0; m < NPTS; ++m) {
                float x = dist2(Qf, pb[m]);
                int  xi = m;
                if (x < bd[15] || (x == bd[15] && xi < bi[15])) {
#pragma unroll
                    for (int t = 0; t < 16; ++t) {
                        bool cc = (x < bd[t]) || (x == bd[t] && xi < bi[t]);
                        float nd = cc ? x  : bd[t];
                        int   ni = cc ? xi : bi[t];
                        float od = cc ? bd[t] : x;
                        int   oi = cc ? bi[t] : xi;
                        bd[t] = nd; bi[t] = ni; x = od; xi = oi;
                    }
                }
            }
        }
        int* op = idxout + ((size_t)b * NPTS + nqf) * KNN;
#pragma unroll
        for (int j = 0; j < 16; ++j) op[j] = bi[j];
    }
}

// ---------------------------------------------------------------------------
// Kernel B: fully-register MFMA MLP (unchanged from rounds 4-16).
// ---------------------------------------------------------------------------
__global__ __launch_bounds__(256, 2) void mlp_kernel(
    const float4* __restrict__ pts4, const int* __restrict__ idxin,
    const float* __restrict__ W0, const float* __restrict__ b0,
    const float* __restrict__ W1, const float* __restrict__ b1,
    const float* __restrict__ W2, const float* __restrict__ b2,
    float* __restrict__ out) {

    int tid  = threadIdx.x;
    int wave = tid >> 6, lane = tid & 63;
    int g = lane >> 4, i = lane & 15;

    h2 w0x[8], w0y[8], w0z[8], w0b[8];
#pragma unroll
    for (int s = 0; s < 2; ++s)
#pragma unroll
        for (int v = 0; v < 4; ++v) {
            int c0 = 32 * s + 8 * g + 2 * v;
            w0x[s * 4 + v] = pk2(W0[c0 * 3 + 0], W0[c0 * 3 + 3]);
            w0y[s * 4 + v] = pk2(W0[c0 * 3 + 1], W0[c0 * 3 + 4]);
            w0z[s * 4 + v] = pk2(W0[c0 * 3 + 2], W0[c0 * 3 + 5]);
            w0b[s * 4 + v] = pk2(b0[c0], b0[c0 + 1]);
        }
    h2 b1p[8];
#pragma unroll
    for (int s = 0; s < 2; ++s)
#pragma unroll
        for (int v = 0; v < 4; ++v) {
            int c0 = 32 * s + 16 * (v >> 1) + 4 * g + 2 * (v & 1);
            b1p[s * 4 + v] = pk2(b1[c0], b1[c0 + 1]);
        }
    h8 wf1[4][2];
#pragma unroll
    for (int t = 0; t < 4; ++t)
#pragma unroll
        for (int s = 0; s < 2; ++s) {
            const float* p = W1 + (16 * t + i) * 64 + 32 * s + 8 * g;
            h8 f;
#pragma unroll
            for (int j = 0; j < 8; ++j) f[j] = (_Float16)p[j];
            wf1[t][s] = f;
        }
    h8 wf2[8][2];
#pragma unroll
    for (int t = 0; t < 8; ++t)
#pragma unroll
        for (int s = 0; s < 2; ++s) {
            const float* p = W2 + (16 * t + i) * 64;
            h8 f;
#pragma unroll
            for (int j = 0; j < 8; ++j) {
                int vc = 32 * s + 16 * (j >> 2) + 4 * g + (j & 3);
                f[j] = (_Float16)p[vc];
            }
            wf2[t][s] = f;
        }

    int gw = blockIdx.x * 4 + wave;
    int b  = gw >> 8;
    int n0 = (gw & 255) * 16;

    const float4* pb = pts4 + (size_t)b * NPTS;
    float4 q = pb[n0 + i];
    const int* ip = idxin + ((size_t)b * NPTS + n0 + i) * KNN;

    float mx[8][4];
#pragma unroll
    for (int t = 0; t < 8; ++t)
#pragma unroll
        for (int r = 0; r < 4; ++r) mx[t][r] = -3.4e38f;

    for (int it = 0; it < KNN; ++it) {
        int mi = ip[it];
        float4 p = pb[mi];
        float rx = p.x - q.x, ry = p.y - q.y, rz = p.z - q.z;
        h2 rxx = pk2(rx, rx), ryy = pk2(ry, ry), rzz = pk2(rz, rz);

        h8 h0f[2];
#pragma unroll
        for (int s = 0; s < 2; ++s)
#pragma unroll
            for (int v = 0; v < 4; ++v) {
                h2 hh = __builtin_elementwise_fma(w0z[s * 4 + v], rzz,
                         __builtin_elementwise_fma(w0y[s * 4 + v], ryy,
                          __builtin_elementwise_fma(w0x[s * 4 + v], rxx, w0b[s * 4 + v])));
                hh = __builtin_elementwise_max(hh, (h2)(_Float16)0.0f);
                h0f[s][2 * v]     = hh.x;
                h0f[s][2 * v + 1] = hh.y;
            }

        f4 d1[4];
#pragma unroll
        for (int t = 0; t < 4; ++t) {
            d1[t] = (f4)0.0f;
#pragma unroll
            for (int s = 0; s < 2; ++s)
                d1[t] = __builtin_amdgcn_mfma_f32_16x16x32_f16(wf1[t][s], h0f[s], d1[t], 0, 0, 0);
        }

        h8 h1f[2];
#pragma unroll
        for (int s = 0; s < 2; ++s)
#pragma unroll
            for (int v = 0; v < 4; ++v) {
                int t = 2 * s + (v >> 1), r0 = 2 * (v & 1);
                h2 w = pk2(d1[t][r0], d1[t][r0 + 1]);
                w = w + b1p[s * 4 + v];
                w = __builtin_elementwise_max(w, (h2)(_Float16)0.0f);
                h1f[s][2 * v]     = w.x;
                h1f[s][2 * v + 1] = w.y;
            }

#pragma unroll
        for (int t = 0; t < 8; ++t) {
            f4 d2 = (f4)0.0f;
#pragma unroll
            for (int s = 0; s < 2; ++s)
                d2 = __builtin_amdgcn_mfma_f32_16x16x32_f16(wf2[t][s], h1f[s], d2, 0, 0, 0);
#pragma unroll
            for (int r = 0; r < 4; ++r) mx[t][r] = fmaxf(mx[t][r], d2[r]);
        }
    }

    size_t ob = (size_t)b * 128 * NPTS + n0 + i;
#pragma unroll
    for (int t = 0; t < 8; ++t)
#pragma unroll
        for (int r = 0; r < 4; ++r) {
            int chn = 16 * t + 4 * g + r;
            float v = fmaxf(mx[t][r] + b2[chn], 0.0f);
            out[ob + (size_t)chn * NPTS] = v;
        }
}

// ---------------------------------------------------------------------------
extern "C" void kernel_launch(void* const* d_in, const int* in_sizes, int n_in,
                              void* d_out, int out_size, void* d_ws, size_t ws_size,
                              hipStream_t stream) {
    (void)in_sizes; (void)n_in; (void)out_size; (void)ws_size;
    const float* xyz = (const float*)d_in[0];
    const float* W0  = (const float*)d_in[1];
    const float* b0  = (const float*)d_in[2];
    const float* W1  = (const float*)d_in[3];
    const float* b1  = (const float*)d_in[4];
    const float* W2  = (const float*)d_in[5];
    const float* b2  = (const float*)d_in[6];
    float* out = (float*)d_out;

    char* ws = (char*)d_ws;
    float4*   pts4 = (float4*)ws;                                   // 512 KB
    int*      idxb = (int*)(ws + (512 << 10));                      // 2 MB
    uint2*    pm16 = (uint2*)(ws + (512 << 10) + (2 << 20));        // 256 KB
    unsigned* mxb  = (unsigned*)(ws + (512 << 10) + (2 << 20) + (256 << 10)); // 64 B

    prep_kernel<<<dim3(NB), dim3(1024), 0, stream>>>(xyz, pts4, pm16, mxb);
    knn_kernel<<<dim3(NPTS / QB, NB), dim3(256), 0, stream>>>(pts4, pm16, mxb, idxb);
    mlp_kernel<<<dim3(512), dim3(256), 0, stream>>>(
        pts4, idxb, W0, b0, W1, b1, W2, b2, out);
}